// Round 20
// baseline (228.598 us; speedup 1.0000x reference)
//
#include <hip/hip_runtime.h>

typedef __bf16 bf16_t;
typedef bf16_t bf16x4 __attribute__((ext_vector_type(4)));
typedef bf16_t bf16x8 __attribute__((ext_vector_type(8)));
typedef float f32x4 __attribute__((ext_vector_type(4)));
typedef float f32x8 __attribute__((ext_vector_type(8)));

#define B_N 4
#define S_N 1024
#define E_N 1024
#define H_N 16
#define D_N 64

#define MFMA16 __builtin_amdgcn_mfma_f32_16x16x32_bf16

static __device__ __forceinline__ bf16_t f2b(float x) { return (bf16_t)x; }

// async global->LDS, 16B per lane; lds dest = wave-uniform base + lane*16
static __device__ __forceinline__ void gload_lds16(const void* g, void* l) {
  __builtin_amdgcn_global_load_lds(
      (const __attribute__((address_space(1))) unsigned int*)g,
      (__attribute__((address_space(3))) unsigned int*)l, 16, 0, 0);
}

// LDS-only barrier: waits ds ops, does NOT drain vmcnt.
static __device__ __forceinline__ void lds_barrier() {
  asm volatile("s_waitcnt lgkmcnt(0)\n\ts_barrier" ::: "memory");
  __builtin_amdgcn_sched_barrier(0);
}

// ---------------------------------------------------------------------------
// One-shot fp32 -> bf16 conversion of q,k,v and the four weight matrices.
// ---------------------------------------------------------------------------
__global__ __launch_bounds__(256) void convert_kernel(
    const float* __restrict__ q, const float* __restrict__ k, const float* __restrict__ v,
    const float* __restrict__ wq, const float* __restrict__ wk,
    const float* __restrict__ wv, const float* __restrict__ wo,
    bf16_t* __restrict__ dq, bf16_t* __restrict__ dk, bf16_t* __restrict__ dv,
    bf16_t* __restrict__ dwq, bf16_t* __restrict__ dwk,
    bf16_t* __restrict__ dwv, bf16_t* __restrict__ dwo)
{
  const size_t e = ((size_t)blockIdx.x * 256 + threadIdx.x) * 8;
  const float* src; bf16_t* dst; size_t off;
  if (e < 12582912ull) {                       // q | k | v (4M elems each)
    const int which = (int)(e >> 22);
    off = e & 4194303ull;
    src = which == 0 ? q : (which == 1 ? k : v);
    dst = which == 0 ? dq : (which == 1 ? dk : dv);
  } else {                                     // Wq | Wk | Wv | Wo (1M each)
    const size_t e2 = e - 12582912ull;
    const int which = (int)(e2 >> 20);
    off = e2 & 1048575ull;
    src = which == 0 ? wq : (which == 1 ? wk : (which == 2 ? wv : wo));
    dst = which == 0 ? dwq : (which == 1 ? dwk : (which == 2 ? dwv : dwo));
  }
  f32x8 x = *(const f32x8*)(src + off);
  bf16x8 r;
#pragma unroll
  for (int i = 0; i < 8; ++i) r[i] = f2b(x[i]);
  *(bf16x8*)(dst + off) = r;
}

// ---------------------------------------------------------------------------
// mask row-any precompute: flags[row] = any(mask[row][*]).
// ---------------------------------------------------------------------------
__global__ __launch_bounds__(256) void mask_rowany(
    const unsigned char* __restrict__ mask, unsigned char* __restrict__ flags)
{
  const int row = blockIdx.x * 4 + (threadIdx.x >> 6);
  const int lane = threadIdx.x & 63;
  const uint4 v = *(const uint4*)(mask + (size_t)row * 1024 + lane * 16);
  const unsigned int any = v.x | v.y | v.z | v.w;
  const unsigned long long bal = __ballot(any != 0);
  if (lane == 0) flags[row] = bal ? 1 : 0;
}

// ---------------------------------------------------------------------------
// Batched QKV projection GEMM, m97-style staging (r17 version).
// ---------------------------------------------------------------------------
__global__ __launch_bounds__(256) void qkv_gemm(
    const bf16_t* __restrict__ qA, const bf16_t* __restrict__ kA, const bf16_t* __restrict__ vA,
    const bf16_t* __restrict__ Wq, const bf16_t* __restrict__ Wk, const bf16_t* __restrict__ Wv,
    const float* __restrict__ bq, const float* __restrict__ bk, const float* __restrict__ bv,
    bf16_t* __restrict__ Qo, bf16_t* __restrict__ Ko, bf16_t* __restrict__ Vto)
{
  const int z = blockIdx.z;
  const bf16_t* A = z == 0 ? qA : (z == 1 ? kA : vA);
  const bf16_t* W = z == 0 ? Wq : (z == 1 ? Wk : Wv);
  const float* bias = z == 0 ? bq : (z == 1 ? bk : bv);

  __shared__ bf16_t As[128 * 32];
  __shared__ bf16_t Bs[128 * 32];
  const int tid = threadIdx.x;
  const int m0 = blockIdx.y * 128, n0 = blockIdx.x * 128;
  const int lane = tid & 63, wid = tid >> 6;
  const int wr = wid >> 1, wc = wid & 1;
  const int lr = lane & 15, lh = lane >> 4;
  const int sr = lane >> 2, sc = (lane & 3) * 8;
  f32x4 acc[4][4] = {};
  for (int k0 = 0; k0 < 1024; k0 += 32) {
#pragma unroll
    for (int i = 0; i < 2; ++i) {
      const int br = wid * 32 + i * 16;
      gload_lds16(&A[(size_t)(m0 + br + sr) * 1024 + k0 + sc], &As[br * 32]);
      gload_lds16(&W[(size_t)(n0 + br + sr) * 1024 + k0 + sc], &Bs[br * 32]);
    }
    __syncthreads();
    bf16x8 af[4], bw[4];
#pragma unroll
    for (int m = 0; m < 4; ++m)
      af[m] = *(const bf16x8*)&As[(wr * 64 + m * 16 + lr) * 32 + lh * 8];
#pragma unroll
    for (int n = 0; n < 4; ++n)
      bw[n] = *(const bf16x8*)&Bs[(wc * 64 + n * 16 + lr) * 32 + lh * 8];
#pragma unroll
    for (int m = 0; m < 4; ++m)
#pragma unroll
      for (int n = 0; n < 4; ++n)
        acc[m][n] = MFMA16(af[m], bw[n], acc[m][n], 0, 0, 0);
    __syncthreads();
  }
#pragma unroll
  for (int n = 0; n < 4; ++n) {
    const int col = n0 + wc * 64 + n * 16 + lr;
    const float bv_ = bias[col];
    const int h = col >> 6, d = col & 63;
#pragma unroll
    for (int m = 0; m < 4; ++m) {
      const int row0 = m0 + wr * 64 + m * 16 + lh * 4;
#pragma unroll
      for (int r = 0; r < 4; ++r) {
        const int row = row0 + r;
        const float v = acc[m][n][r] + bv_;
        const int b = row >> 10, s = row & 1023;
        if (z == 0)
          Qo[((size_t)(b * H_N + h) * S_N + s) * D_N + d] = f2b(v);
        else if (z == 1)
          Ko[((size_t)(b * H_N + h) * S_N + s) * D_N + d] = f2b(v);
        else
          Vto[((size_t)(b * H_N + h) * D_N + d) * S_N + s] = f2b(v);
      }
    }
  }
}

// ---------------------------------------------------------------------------
// Output projection: 64x128 tile, 512 blocks = 2/CU (r19 version).
// ---------------------------------------------------------------------------
__global__ __launch_bounds__(256) void out_gemm(
    const bf16_t* __restrict__ A, const bf16_t* __restrict__ W,
    const float* __restrict__ bias, float* __restrict__ Co)
{
  __shared__ bf16_t As[64 * 32];               // 4KB
  __shared__ bf16_t Bs[128 * 32];              // 8KB
  const int tid = threadIdx.x;
  const int m0 = blockIdx.y * 64, n0 = blockIdx.x * 128;
  const int lane = tid & 63, wid = tid >> 6;
  const int lr = lane & 15, lh = lane >> 4;
  const int sr = lane >> 2, sc = (lane & 3) * 8;
  f32x4 acc[4][2] = {};
  for (int k0 = 0; k0 < 1024; k0 += 32) {
    gload_lds16(&A[(size_t)(m0 + wid * 16 + sr) * 1024 + k0 + sc], &As[wid * 16 * 32]);
#pragma unroll
    for (int i = 0; i < 2; ++i) {
      const int br = wid * 32 + i * 16;
      gload_lds16(&W[(size_t)(n0 + br + sr) * 1024 + k0 + sc], &Bs[br * 32]);
    }
    __syncthreads();
    bf16x8 af[4], bw[2];
#pragma unroll
    for (int m = 0; m < 4; ++m)
      af[m] = *(const bf16x8*)&As[(m * 16 + lr) * 32 + lh * 8];
#pragma unroll
    for (int n = 0; n < 2; ++n)
      bw[n] = *(const bf16x8*)&Bs[(wid * 32 + n * 16 + lr) * 32 + lh * 8];
#pragma unroll
    for (int m = 0; m < 4; ++m)
#pragma unroll
      for (int n = 0; n < 2; ++n)
        acc[m][n] = MFMA16(af[m], bw[n], acc[m][n], 0, 0, 0);
    __syncthreads();
  }
#pragma unroll
  for (int n = 0; n < 2; ++n) {
    const int col = n0 + wid * 32 + n * 16 + lr;
    const float bv_ = bias[col];
#pragma unroll
    for (int m = 0; m < 4; ++m) {
      const int row0 = m0 + m * 16 + lh * 4;
#pragma unroll
      for (int r = 0; r < 4; ++r)
        Co[(size_t)(row0 + r) * E_N + col] = acc[m][n][r] + bv_;
    }
  }
}

// ---------------------------------------------------------------------------
// score4: scale + rel_bias (+ mask only if um) for 4 consecutive k.
// ---------------------------------------------------------------------------
static __device__ __forceinline__ f32x4 score4(
    f32x4 acc, int qrow, int kc, const unsigned char* __restrict__ mrow,
    const float* __restrict__ rbh, float rb_lo, float rb_hi, bool um)
{
  const int d0 = kc - qrow;
  float b0, b1, b2, b3;
  if (d0 >= 8) { b0 = b1 = b2 = b3 = rb_hi; }
  else if (d0 <= -11) { b0 = b1 = b2 = b3 = rb_lo; }
  else {
    int dd;
    dd = d0;     dd = dd < -8 ? -8 : (dd > 8 ? 8 : dd); b0 = rbh[dd + 8];
    dd = d0 + 1; dd = dd < -8 ? -8 : (dd > 8 ? 8 : dd); b1 = rbh[dd + 8];
    dd = d0 + 2; dd = dd < -8 ? -8 : (dd > 8 ? 8 : dd); b2 = rbh[dd + 8];
    dd = d0 + 3; dd = dd < -8 ? -8 : (dd > 8 ? 8 : dd); b3 = rbh[dd + 8];
  }
  f32x4 s;
  s[0] = acc[0] * 0.125f + b0;
  s[1] = acc[1] * 0.125f + b1;
  s[2] = acc[2] * 0.125f + b2;
  s[3] = acc[3] * 0.125f + b3;
  if (um) {
    const unsigned int mw = *(const unsigned int*)(mrow + kc);
    const float NEG = -__builtin_inff();
    if (mw & 0xffu)       s[0] = NEG;
    if (mw & 0xff00u)     s[1] = NEG;
    if (mw & 0xff0000u)   s[2] = NEG;
    if (mw & 0xff000000u) s[3] = NEG;
  }
  return s;
}

// ---------------------------------------------------------------------------
// Fused attention (r17 + halved S_lds -> 3 blocks/CU):
// S_lds holds 32 k-cols (pitch 36); each 64-k tile is processed as two
// halves {compute 2x16-k -> S_lds -> coalesced NT store (8 rows x 128B
// full lines)}. PV consumes p per half (ch = half). LDS total 50KB:
// K/V dbuf 32KB + S_lds 18KB -> 3 blocks/CU (24 waves, was 16).
// __launch_bounds__(512,6) holds VGPR <= ~84 so the 3rd block fits.
// ---------------------------------------------------------------------------
__global__ __launch_bounds__(512, 6) void fused_attn(
    const bf16_t* __restrict__ Q, const bf16_t* __restrict__ K,
    const bf16_t* __restrict__ Vt,
    const unsigned char* __restrict__ mask, const unsigned char* __restrict__ rowflag,
    const float* __restrict__ rel_bias,
    float* __restrict__ scores, float* __restrict__ attn, bf16_t* __restrict__ ctx)
{
  __shared__ bf16_t Ktile[2][64 * 64];         // 16KB double-buffered
  __shared__ bf16_t Vtile[2][64 * 64];         // 16KB double-buffered
  __shared__ float S_lds[8][16][36];           // 18KB per-wave half-tile

  // T1: bijective XCD swizzle (nwg = 512, 512 % 8 == 0, chunk = 64)
  int flat = blockIdx.y * 4 + blockIdx.x;      // 0..511
  flat = (flat & 7) * 64 + (flat >> 3);
  const int bh = flat >> 3, b = bh >> 4, h = bh & 15;
  const int q0 = (flat & 7) * 128;

  const int tid = threadIdx.x;
  const int w = tid >> 6, lane = tid & 63;
  const int lr = lane & 15, lh = lane >> 4;
  const int qrow = q0 + w * 16 + lr;

  const bf16_t* Qh = Q + (size_t)bh * (S_N * D_N);
  const bf16_t* Kh = K + (size_t)bh * (S_N * D_N);
  const bf16_t* Vh = Vt + (size_t)bh * (D_N * S_N);
  const unsigned char* mrow = mask + (size_t)b * S_N * S_N + (size_t)qrow * S_N;
  float* Sbase = scores + (size_t)bh * S_N * S_N + (size_t)(q0 + w * 16) * S_N;
  float* Abase = attn + (size_t)bh * S_N * S_N + (size_t)(q0 + w * 16) * S_N;
  const float* rbh = rel_bias + h * 17;
  const float rb_lo = rbh[0], rb_hi = rbh[16];
  const float NEG = -__builtin_inff();
  const float THR = 8.0f;
  const bool um = rowflag[b * S_N + qrow] != 0;

  // staging coords: 512 threads x 1 granule (16B) = 64 rows x 8 granules
  const int sg_row = tid >> 3, sg_c = tid & 7;
  const int sg_s = (sg_c ^ (sg_row & 7)) * 8;
  // transpose-store coords: 8 rows x 32 cols per instruction (128B lines)
  const int st_r = lane >> 3, st_c = (lane & 7) * 4;

  bf16x8 qa0 = *(const bf16x8*)&Qh[(size_t)qrow * D_N + lh * 8];
  bf16x8 qa1 = *(const bf16x8*)&Qh[(size_t)qrow * D_N + 32 + lh * 8];

  const int ks0 = (lh ^ (lr & 7)) * 8;
  const int ks1 = ((4 + lh) ^ (lr & 7)) * 8;

  // ---- P1: scores + deferred-max online (max,sum) --------------------------
  float mrun = NEG, srun = 0.f;
  *(bf16x8*)&Ktile[0][sg_row * 64 + sg_s] =
      *(const bf16x8*)&Kh[(size_t)sg_row * D_N + sg_c * 8];
  lds_barrier();
  for (int kt = 0; kt < 16; ++kt) {
    const int cur = kt & 1, kb = kt * 64;
    bf16x8 krn;
    if (kt + 1 < 16)
      krn = *(const bf16x8*)&Kh[(size_t)(kb + 64 + sg_row) * D_N + sg_c * 8];
    f32x4 sr4[4];
#pragma unroll
    for (int half = 0; half < 2; ++half) {
#pragma unroll
      for (int th = 0; th < 2; ++th) {
        const int t = half * 2 + th;
        const int krow = t * 16 + lr;
        bf16x8 ka0 = *(const bf16x8*)&Ktile[cur][krow * 64 + ks0];
        bf16x8 ka1 = *(const bf16x8*)&Ktile[cur][krow * 64 + ks1];
        f32x4 acc = {};
        acc = MFMA16(ka0, qa0, acc, 0, 0, 0);  // D[k][q]
        acc = MFMA16(ka1, qa1, acc, 0, 0, 0);
        const int kc = kb + t * 16 + 4 * lh;
        f32x4 s = score4(acc, qrow, kc, mrow, rbh, rb_lo, rb_hi, um);
        sr4[t] = s;
        *(f32x4*)&S_lds[w][lr][th * 16 + 4 * lh] = s;
      }
      // coalesced NT store of this 16-row x 32-col half (full 128B lines)
#pragma unroll
      for (int i = 0; i < 2; ++i) {
        const int row = 8 * i + st_r;
        f32x4 sv = *(const f32x4*)&S_lds[w][row][st_c];
        __builtin_nontemporal_store(sv,
            (f32x4*)&Sbase[(size_t)row * S_N + kb + half * 32 + st_c]);
      }
    }
    float mloc = NEG;
#pragma unroll
    for (int t = 0; t < 4; ++t)
      mloc = fmaxf(mloc, fmaxf(fmaxf(sr4[t][0], sr4[t][1]), fmaxf(sr4[t][2], sr4[t][3])));
    mloc = fmaxf(mloc, __shfl_xor(mloc, 16));
    mloc = fmaxf(mloc, __shfl_xor(mloc, 32));
    if (__any(mloc - mrun > THR)) {
      const float mn = fmaxf(mrun, mloc);
      if (mn > NEG) {
        srun = srun * __expf(mrun - mn);
        mrun = mn;
      }
    }
    const bool live = mrun > NEG;
    float ls = 0.f;
#pragma unroll
    for (int t = 0; t < 4; ++t) {
      f32x4 s = sr4[t];
      float e0 = live ? __expf(s[0] - mrun) : 0.f;
      float e1 = live ? __expf(s[1] - mrun) : 0.f;
      float e2 = live ? __expf(s[2] - mrun) : 0.f;
      float e3 = live ? __expf(s[3] - mrun) : 0.f;
      ls += (e0 + e1) + (e2 + e3);
    }
    srun += ls;
    if (kt + 1 < 16)
      *(bf16x8*)&Ktile[cur ^ 1][sg_row * 64 + sg_s] = krn;
    lds_barrier();
  }
  srun += __shfl_xor(srun, 16);
  srun += __shfl_xor(srun, 32);
  const float M = mrun;
  const float invs = 1.0f / srun;

  // ---- P2: recompute, NT attn write (per half), PV (ch = half) -------------
  f32x4 accp[4] = {};
  *(bf16x8*)&Ktile[0][sg_row * 64 + sg_s] =
      *(const bf16x8*)&Kh[(size_t)sg_row * D_N + sg_c * 8];
  *(bf16x8*)&Vtile[0][sg_row * 64 + sg_s] =
      *(const bf16x8*)&Vh[(size_t)sg_row * S_N + sg_c * 8];
  lds_barrier();
  for (int kt = 0; kt < 16; ++kt) {
    const int cur = kt & 1, kb = kt * 64;
    bf16x8 krn, vrn;
    if (kt + 1 < 16) {
      krn = *(const bf16x8*)&Kh[(size_t)(kb + 64 + sg_row) * D_N + sg_c * 8];
      vrn = *(const bf16x8*)&Vh[(size_t)sg_row * S_N + kb + 64 + sg_c * 8];
    }
#pragma unroll
    for (int half = 0; half < 2; ++half) {
#pragma unroll
      for (int th = 0; th < 2; ++th) {
        const int t = half * 2 + th;
        const int krow = t * 16 + lr;
        bf16x8 ka0 = *(const bf16x8*)&Ktile[cur][krow * 64 + ks0];
        bf16x8 ka1 = *(const bf16x8*)&Ktile[cur][krow * 64 + ks1];
        f32x4 acc = {};
        acc = MFMA16(ka0, qa0, acc, 0, 0, 0);
        acc = MFMA16(ka1, qa1, acc, 0, 0, 0);
        const int kc = kb + t * 16 + 4 * lh;
        f32x4 s = score4(acc, qrow, kc, mrow, rbh, rb_lo, rb_hi, um);
        f32x4 p;
#pragma unroll
        for (int j = 0; j < 4; ++j) p[j] = __expf(s[j] - M) * invs;
        *(f32x4*)&S_lds[w][lr][th * 16 + 4 * lh] = p;
      }
      // coalesced NT attn store of this half
#pragma unroll
      for (int i = 0; i < 2; ++i) {
        const int row = 8 * i + st_r;
        f32x4 pv = *(const f32x4*)&S_lds[w][row][st_c];
        __builtin_nontemporal_store(pv,
            (f32x4*)&Abase[(size_t)row * S_N + kb + half * 32 + st_c]);
      }
      // PV for this 32-k half
      f32x8 pf = *(const f32x8*)&S_lds[w][lr][lh * 8];
      bf16x8 pa;
#pragma unroll
      for (int j = 0; j < 8; ++j) pa[j] = f2b(pf[j]);
#pragma unroll
      for (int dt = 0; dt < 4; ++dt) {
        const int drow = dt * 16 + lr;
        bf16x8 vb = *(const bf16x8*)&Vtile[cur][drow * 64 + (((half * 4 + lh) ^ (lr & 7)) * 8)];
        accp[dt] = MFMA16(pa, vb, accp[dt], 0, 0, 0);    // D[q][d]
      }
    }
    if (kt + 1 < 16) {
      *(bf16x8*)&Ktile[cur ^ 1][sg_row * 64 + sg_s] = krn;
      *(bf16x8*)&Vtile[cur ^ 1][sg_row * 64 + sg_s] = vrn;
    }
    lds_barrier();
  }
#pragma unroll
  for (int dt = 0; dt < 4; ++dt)
#pragma unroll
    for (int r = 0; r < 4; ++r)
      ctx[((size_t)(b * S_N + q0 + w * 16 + 4 * lh + r)) * E_N + h * 64 + dt * 16 + lr] =
          f2b(accp[dt][r]);
}

// ---------------------------------------------------------------------------
extern "C" void kernel_launch(void* const* d_in, const int* in_sizes, int n_in,
                              void* d_out, int out_size, void* d_ws, size_t ws_size,
                              hipStream_t stream) {
  (void)in_sizes; (void)n_in; (void)out_size; (void)ws_size;
  const float* query = (const float*)d_in[0];
  const float* key   = (const float*)d_in[1];
  const float* value = (const float*)d_in[2];
  const unsigned char* mask = (const unsigned char*)d_in[3];
  const float* Wq = (const float*)d_in[4];
  const float* bq = (const float*)d_in[5];
  const float* Wk = (const float*)d_in[6];
  const float* bk = (const float*)d_in[7];
  const float* Wv = (const float*)d_in[8];
  const float* bv = (const float*)d_in[9];
  const float* Wo = (const float*)d_in[10];
  const float* bo = (const float*)d_in[11];
  const float* rel_bias = (const float*)d_in[12];

  float* out_f    = (float*)d_out;                     //  4,194,304 floats
  float* attn_f   = out_f + (size_t)4194304;           // 67,108,864 floats
  float* scores_f = attn_f + (size_t)67108864;         // 67,108,864 floats

  char* ws = (char*)d_ws;                              // ~2GiB; 65MB used
  bf16_t* qbf  = (bf16_t*)(ws);                        // (4096,1024) 8MB
  bf16_t* kbf  = (bf16_t*)(ws + (8ull  << 20));        // 8MB
  bf16_t* vbf  = (bf16_t*)(ws + (16ull << 20));        // 8MB
  bf16_t* Wqb  = (bf16_t*)(ws + (24ull << 20));        // 2MB
  bf16_t* Wkb  = (bf16_t*)(ws + (26ull << 20));        // 2MB
  bf16_t* Wvb  = (bf16_t*)(ws + (28ull << 20));        // 2MB
  bf16_t* Wob  = (bf16_t*)(ws + (30ull << 20));        // 2MB
  bf16_t* Qbf  = (bf16_t*)(ws + (32ull << 20));        // (B,H,S,D) 8MB
  bf16_t* Kbf  = (bf16_t*)(ws + (40ull << 20));        // (B,H,S,D) 8MB
  bf16_t* Vtbf = (bf16_t*)(ws + (48ull << 20));        // (B,H,D,S) 8MB
  bf16_t* CTX  = (bf16_t*)(ws + (56ull << 20));        // (B,S,E)   8MB
  unsigned char* FLAGS = (unsigned char*)(ws + (64ull << 20)); // 4KB

  convert_kernel<<<dim3(8192), dim3(256), 0, stream>>>(
      query, key, value, Wq, Wk, Wv, Wo, qbf, kbf, vbf, Wqb, Wkb, Wvb, Wob);
  mask_rowany<<<dim3(1024), dim3(256), 0, stream>>>(mask, FLAGS);
  qkv_gemm<<<dim3(8, 32, 3), dim3(256), 0, stream>>>(
      qbf, kbf, vbf, Wqb, Wkb, Wvb, bq, bk, bv, Qbf, Kbf, Vtbf);
  fused_attn<<<dim3(4, 128), dim3(512), 0, stream>>>(
      Qbf, Kbf, Vtbf, mask, FLAGS, rel_bias, scores_f, attn_f, CTX);
  out_gemm<<<dim3(8, 64), dim3(256), 0, stream>>>(CTX, Wob, bo, out_f);
}

// Round 21
// 210.173 us; speedup vs baseline: 1.0877x; 1.0877x over previous
//
#include <hip/hip_runtime.h>

typedef __bf16 bf16_t;
typedef bf16_t bf16x4 __attribute__((ext_vector_type(4)));
typedef bf16_t bf16x8 __attribute__((ext_vector_type(8)));
typedef float f32x4 __attribute__((ext_vector_type(4)));
typedef float f32x8 __attribute__((ext_vector_type(8)));

#define B_N 4
#define S_N 1024
#define E_N 1024
#define H_N 16
#define D_N 64

#define MFMA16 __builtin_amdgcn_mfma_f32_16x16x32_bf16

static __device__ __forceinline__ bf16_t f2b(float x) { return (bf16_t)x; }

// async global->LDS, 16B per lane; lds dest = wave-uniform base + lane*16
static __device__ __forceinline__ void gload_lds16(const void* g, void* l) {
  __builtin_amdgcn_global_load_lds(
      (const __attribute__((address_space(1))) unsigned int*)g,
      (__attribute__((address_space(3))) unsigned int*)l, 16, 0, 0);
}

// LDS-only barrier: waits ds ops, does NOT drain vmcnt.
static __device__ __forceinline__ void lds_barrier() {
  asm volatile("s_waitcnt lgkmcnt(0)\n\ts_barrier" ::: "memory");
  __builtin_amdgcn_sched_barrier(0);
}

// ---------------------------------------------------------------------------
// One-shot fp32 -> bf16 conversion of q,k,v and the four weight matrices.
// ---------------------------------------------------------------------------
__global__ __launch_bounds__(256) void convert_kernel(
    const float* __restrict__ q, const float* __restrict__ k, const float* __restrict__ v,
    const float* __restrict__ wq, const float* __restrict__ wk,
    const float* __restrict__ wv, const float* __restrict__ wo,
    bf16_t* __restrict__ dq, bf16_t* __restrict__ dk, bf16_t* __restrict__ dv,
    bf16_t* __restrict__ dwq, bf16_t* __restrict__ dwk,
    bf16_t* __restrict__ dwv, bf16_t* __restrict__ dwo)
{
  const size_t e = ((size_t)blockIdx.x * 256 + threadIdx.x) * 8;
  const float* src; bf16_t* dst; size_t off;
  if (e < 12582912ull) {                       // q | k | v (4M elems each)
    const int which = (int)(e >> 22);
    off = e & 4194303ull;
    src = which == 0 ? q : (which == 1 ? k : v);
    dst = which == 0 ? dq : (which == 1 ? dk : dv);
  } else {                                     // Wq | Wk | Wv | Wo (1M each)
    const size_t e2 = e - 12582912ull;
    const int which = (int)(e2 >> 20);
    off = e2 & 1048575ull;
    src = which == 0 ? wq : (which == 1 ? wk : (which == 2 ? wv : wo));
    dst = which == 0 ? dwq : (which == 1 ? dwk : (which == 2 ? dwv : dwo));
  }
  f32x8 x = *(const f32x8*)(src + off);
  bf16x8 r;
#pragma unroll
  for (int i = 0; i < 8; ++i) r[i] = f2b(x[i]);
  *(bf16x8*)(dst + off) = r;
}

// ---------------------------------------------------------------------------
// mask row-any precompute: flags[row] = any(mask[row][*]).
// ---------------------------------------------------------------------------
__global__ __launch_bounds__(256) void mask_rowany(
    const unsigned char* __restrict__ mask, unsigned char* __restrict__ flags)
{
  const int row = blockIdx.x * 4 + (threadIdx.x >> 6);
  const int lane = threadIdx.x & 63;
  const uint4 v = *(const uint4*)(mask + (size_t)row * 1024 + lane * 16);
  const unsigned int any = v.x | v.y | v.z | v.w;
  const unsigned long long bal = __ballot(any != 0);
  if (lane == 0) flags[row] = bal ? 1 : 0;
}

// ---------------------------------------------------------------------------
// Batched QKV projection GEMM, m97-style staging (r17 version).
// ---------------------------------------------------------------------------
__global__ __launch_bounds__(256) void qkv_gemm(
    const bf16_t* __restrict__ qA, const bf16_t* __restrict__ kA, const bf16_t* __restrict__ vA,
    const bf16_t* __restrict__ Wq, const bf16_t* __restrict__ Wk, const bf16_t* __restrict__ Wv,
    const float* __restrict__ bq, const float* __restrict__ bk, const float* __restrict__ bv,
    bf16_t* __restrict__ Qo, bf16_t* __restrict__ Ko, bf16_t* __restrict__ Vto)
{
  const int z = blockIdx.z;
  const bf16_t* A = z == 0 ? qA : (z == 1 ? kA : vA);
  const bf16_t* W = z == 0 ? Wq : (z == 1 ? Wk : Wv);
  const float* bias = z == 0 ? bq : (z == 1 ? bk : bv);

  __shared__ bf16_t As[128 * 32];
  __shared__ bf16_t Bs[128 * 32];
  const int tid = threadIdx.x;
  const int m0 = blockIdx.y * 128, n0 = blockIdx.x * 128;
  const int lane = tid & 63, wid = tid >> 6;
  const int wr = wid >> 1, wc = wid & 1;
  const int lr = lane & 15, lh = lane >> 4;
  const int sr = lane >> 2, sc = (lane & 3) * 8;
  f32x4 acc[4][4] = {};
  for (int k0 = 0; k0 < 1024; k0 += 32) {
#pragma unroll
    for (int i = 0; i < 2; ++i) {
      const int br = wid * 32 + i * 16;
      gload_lds16(&A[(size_t)(m0 + br + sr) * 1024 + k0 + sc], &As[br * 32]);
      gload_lds16(&W[(size_t)(n0 + br + sr) * 1024 + k0 + sc], &Bs[br * 32]);
    }
    __syncthreads();
    bf16x8 af[4], bw[4];
#pragma unroll
    for (int m = 0; m < 4; ++m)
      af[m] = *(const bf16x8*)&As[(wr * 64 + m * 16 + lr) * 32 + lh * 8];
#pragma unroll
    for (int n = 0; n < 4; ++n)
      bw[n] = *(const bf16x8*)&Bs[(wc * 64 + n * 16 + lr) * 32 + lh * 8];
#pragma unroll
    for (int m = 0; m < 4; ++m)
#pragma unroll
      for (int n = 0; n < 4; ++n)
        acc[m][n] = MFMA16(af[m], bw[n], acc[m][n], 0, 0, 0);
    __syncthreads();
  }
#pragma unroll
  for (int n = 0; n < 4; ++n) {
    const int col = n0 + wc * 64 + n * 16 + lr;
    const float bv_ = bias[col];
    const int h = col >> 6, d = col & 63;
#pragma unroll
    for (int m = 0; m < 4; ++m) {
      const int row0 = m0 + wr * 64 + m * 16 + lh * 4;
#pragma unroll
      for (int r = 0; r < 4; ++r) {
        const int row = row0 + r;
        const float v = acc[m][n][r] + bv_;
        const int b = row >> 10, s = row & 1023;
        if (z == 0)
          Qo[((size_t)(b * H_N + h) * S_N + s) * D_N + d] = f2b(v);
        else if (z == 1)
          Ko[((size_t)(b * H_N + h) * S_N + s) * D_N + d] = f2b(v);
        else
          Vto[((size_t)(b * H_N + h) * D_N + d) * S_N + s] = f2b(v);
      }
    }
  }
}

// ---------------------------------------------------------------------------
// Output projection: 64x128 tile -> 512 blocks = 2/CU (the 128^2 version
// ran at 1 block/CU with naked barrier latency). Wave w covers cols
// [32w, 32w+32); acc[4][2] per wave.
// ---------------------------------------------------------------------------
__global__ __launch_bounds__(256) void out_gemm(
    const bf16_t* __restrict__ A, const bf16_t* __restrict__ W,
    const float* __restrict__ bias, float* __restrict__ Co)
{
  __shared__ bf16_t As[64 * 32];               // 4KB
  __shared__ bf16_t Bs[128 * 32];              // 8KB
  const int tid = threadIdx.x;
  const int m0 = blockIdx.y * 64, n0 = blockIdx.x * 128;
  const int lane = tid & 63, wid = tid >> 6;
  const int lr = lane & 15, lh = lane >> 4;
  const int sr = lane >> 2, sc = (lane & 3) * 8;
  f32x4 acc[4][2] = {};
  for (int k0 = 0; k0 < 1024; k0 += 32) {
    gload_lds16(&A[(size_t)(m0 + wid * 16 + sr) * 1024 + k0 + sc], &As[wid * 16 * 32]);
#pragma unroll
    for (int i = 0; i < 2; ++i) {
      const int br = wid * 32 + i * 16;
      gload_lds16(&W[(size_t)(n0 + br + sr) * 1024 + k0 + sc], &Bs[br * 32]);
    }
    __syncthreads();
    bf16x8 af[4], bw[2];
#pragma unroll
    for (int m = 0; m < 4; ++m)
      af[m] = *(const bf16x8*)&As[(m * 16 + lr) * 32 + lh * 8];
#pragma unroll
    for (int n = 0; n < 2; ++n)
      bw[n] = *(const bf16x8*)&Bs[(wid * 32 + n * 16 + lr) * 32 + lh * 8];
#pragma unroll
    for (int m = 0; m < 4; ++m)
#pragma unroll
      for (int n = 0; n < 2; ++n)
        acc[m][n] = MFMA16(af[m], bw[n], acc[m][n], 0, 0, 0);
    __syncthreads();
  }
#pragma unroll
  for (int n = 0; n < 2; ++n) {
    const int col = n0 + wid * 32 + n * 16 + lr;
    const float bv_ = bias[col];
#pragma unroll
    for (int m = 0; m < 4; ++m) {
      const int row0 = m0 + m * 16 + lh * 4;
#pragma unroll
      for (int r = 0; r < 4; ++r)
        Co[(size_t)(row0 + r) * E_N + col] = acc[m][n][r] + bv_;
    }
  }
}

// ---------------------------------------------------------------------------
// score4: scale + rel_bias (+ mask only if um) for 4 consecutive k.
// ---------------------------------------------------------------------------
static __device__ __forceinline__ f32x4 score4(
    f32x4 acc, int qrow, int kc, const unsigned char* __restrict__ mrow,
    const float* __restrict__ rbh, float rb_lo, float rb_hi, bool um)
{
  const int d0 = kc - qrow;
  float b0, b1, b2, b3;
  if (d0 >= 8) { b0 = b1 = b2 = b3 = rb_hi; }
  else if (d0 <= -11) { b0 = b1 = b2 = b3 = rb_lo; }
  else {
    int dd;
    dd = d0;     dd = dd < -8 ? -8 : (dd > 8 ? 8 : dd); b0 = rbh[dd + 8];
    dd = d0 + 1; dd = dd < -8 ? -8 : (dd > 8 ? 8 : dd); b1 = rbh[dd + 8];
    dd = d0 + 2; dd = dd < -8 ? -8 : (dd > 8 ? 8 : dd); b2 = rbh[dd + 8];
    dd = d0 + 3; dd = dd < -8 ? -8 : (dd > 8 ? 8 : dd); b3 = rbh[dd + 8];
  }
  f32x4 s;
  s[0] = acc[0] * 0.125f + b0;
  s[1] = acc[1] * 0.125f + b1;
  s[2] = acc[2] * 0.125f + b2;
  s[3] = acc[3] * 0.125f + b3;
  if (um) {
    const unsigned int mw = *(const unsigned int*)(mrow + kc);
    const float NEG = -__builtin_inff();
    if (mw & 0xffu)       s[0] = NEG;
    if (mw & 0xff00u)     s[1] = NEG;
    if (mw & 0xff0000u)   s[2] = NEG;
    if (mw & 0xff000000u) s[3] = NEG;
  }
  return s;
}

// ---------------------------------------------------------------------------
// Fused attention (r17/r19 version): double-buffered K/V, one barrier
// per tile, 512 thr / 128 q-rows, XCD-bijective swizzle, NT stores,
// defer-max softmax.
// ---------------------------------------------------------------------------
__global__ __launch_bounds__(512) void fused_attn(
    const bf16_t* __restrict__ Q, const bf16_t* __restrict__ K,
    const bf16_t* __restrict__ Vt,
    const unsigned char* __restrict__ mask, const unsigned char* __restrict__ rowflag,
    const float* __restrict__ rel_bias,
    float* __restrict__ scores, float* __restrict__ attn, bf16_t* __restrict__ ctx)
{
  __shared__ bf16_t Ktile[2][64 * 64];         // 16KB double-buffered
  __shared__ bf16_t Vtile[2][64 * 64];         // 16KB double-buffered
  __shared__ float S_lds[8][16][68];           // 34.8KB per-wave transpose tiles

  // T1: bijective XCD swizzle (nwg = 512, 512 % 8 == 0, chunk = 64)
  int flat = blockIdx.y * 4 + blockIdx.x;      // 0..511
  flat = (flat & 7) * 64 + (flat >> 3);
  const int bh = flat >> 3, b = bh >> 4, h = bh & 15;
  const int q0 = (flat & 7) * 128;

  const int tid = threadIdx.x;
  const int w = tid >> 6, lane = tid & 63;
  const int lr = lane & 15, lh = lane >> 4;
  const int qrow = q0 + w * 16 + lr;

  const bf16_t* Qh = Q + (size_t)bh * (S_N * D_N);
  const bf16_t* Kh = K + (size_t)bh * (S_N * D_N);
  const bf16_t* Vh = Vt + (size_t)bh * (D_N * S_N);
  const unsigned char* mrow = mask + (size_t)b * S_N * S_N + (size_t)qrow * S_N;
  float* Sbase = scores + (size_t)bh * S_N * S_N + (size_t)(q0 + w * 16) * S_N;
  float* Abase = attn + (size_t)bh * S_N * S_N + (size_t)(q0 + w * 16) * S_N;
  const float* rbh = rel_bias + h * 17;
  const float rb_lo = rbh[0], rb_hi = rbh[16];
  const float NEG = -__builtin_inff();
  const float THR = 8.0f;
  const bool um = rowflag[b * S_N + qrow] != 0;

  // staging coords: 512 threads x 1 granule (16B) = 64 rows x 8 granules
  const int sg_row = tid >> 3, sg_c = tid & 7;
  const int sg_s = (sg_c ^ (sg_row & 7)) * 8;

  bf16x8 qa0 = *(const bf16x8*)&Qh[(size_t)qrow * D_N + lh * 8];
  bf16x8 qa1 = *(const bf16x8*)&Qh[(size_t)qrow * D_N + 32 + lh * 8];

  const int ks0 = (lh ^ (lr & 7)) * 8;
  const int ks1 = ((4 + lh) ^ (lr & 7)) * 8;

  // ---- P1: scores + deferred-max online (max,sum) --------------------------
  float mrun = NEG, srun = 0.f;
  *(bf16x8*)&Ktile[0][sg_row * 64 + sg_s] =
      *(const bf16x8*)&Kh[(size_t)sg_row * D_N + sg_c * 8];
  lds_barrier();
  for (int kt = 0; kt < 16; ++kt) {
    const int cur = kt & 1, kb = kt * 64;
    bf16x8 krn;
    if (kt + 1 < 16)
      krn = *(const bf16x8*)&Kh[(size_t)(kb + 64 + sg_row) * D_N + sg_c * 8];
    f32x4 sr4[4];
    float mloc = NEG;
#pragma unroll
    for (int t = 0; t < 4; ++t) {
      const int krow = t * 16 + lr;
      bf16x8 ka0 = *(const bf16x8*)&Ktile[cur][krow * 64 + ks0];
      bf16x8 ka1 = *(const bf16x8*)&Ktile[cur][krow * 64 + ks1];
      f32x4 acc = {};
      acc = MFMA16(ka0, qa0, acc, 0, 0, 0);    // D[k][q]
      acc = MFMA16(ka1, qa1, acc, 0, 0, 0);
      const int kc = kb + t * 16 + 4 * lh;
      f32x4 s = score4(acc, qrow, kc, mrow, rbh, rb_lo, rb_hi, um);
      sr4[t] = s;
      *(f32x4*)&S_lds[w][lr][t * 16 + 4 * lh] = s;
      mloc = fmaxf(mloc, fmaxf(fmaxf(s[0], s[1]), fmaxf(s[2], s[3])));
    }
    mloc = fmaxf(mloc, __shfl_xor(mloc, 16));
    mloc = fmaxf(mloc, __shfl_xor(mloc, 32));
    if (__any(mloc - mrun > THR)) {
      const float mn = fmaxf(mrun, mloc);
      if (mn > NEG) {
        srun = srun * __expf(mrun - mn);
        mrun = mn;
      }
    }
    const bool live = mrun > NEG;
    float ls = 0.f;
#pragma unroll
    for (int t = 0; t < 4; ++t) {
      f32x4 s = sr4[t];
      float e0 = live ? __expf(s[0] - mrun) : 0.f;
      float e1 = live ? __expf(s[1] - mrun) : 0.f;
      float e2 = live ? __expf(s[2] - mrun) : 0.f;
      float e3 = live ? __expf(s[3] - mrun) : 0.f;
      ls += (e0 + e1) + (e2 + e3);
    }
    srun += ls;
#pragma unroll
    for (int i = 0; i < 4; ++i) {
      const int row = 4 * i + lh;
      f32x4 sv = *(const f32x4*)&S_lds[w][row][lr * 4];
      __builtin_nontemporal_store(sv, (f32x4*)&Sbase[(size_t)row * S_N + kb + lr * 4]);
    }
    if (kt + 1 < 16)
      *(bf16x8*)&Ktile[cur ^ 1][sg_row * 64 + sg_s] = krn;
    lds_barrier();
  }
  srun += __shfl_xor(srun, 16);
  srun += __shfl_xor(srun, 32);
  const float M = mrun;
  const float invs = 1.0f / srun;

  // ---- P2: recompute, NT attn write, PV ------------------------------------
  f32x4 accp[4] = {};
  *(bf16x8*)&Ktile[0][sg_row * 64 + sg_s] =
      *(const bf16x8*)&Kh[(size_t)sg_row * D_N + sg_c * 8];
  *(bf16x8*)&Vtile[0][sg_row * 64 + sg_s] =
      *(const bf16x8*)&Vh[(size_t)sg_row * S_N + sg_c * 8];
  lds_barrier();
  for (int kt = 0; kt < 16; ++kt) {
    const int cur = kt & 1, kb = kt * 64;
    bf16x8 krn, vrn;
    if (kt + 1 < 16) {
      krn = *(const bf16x8*)&Kh[(size_t)(kb + 64 + sg_row) * D_N + sg_c * 8];
      vrn = *(const bf16x8*)&Vh[(size_t)sg_row * S_N + kb + 64 + sg_c * 8];
    }
#pragma unroll
    for (int t = 0; t < 4; ++t) {
      const int krow = t * 16 + lr;
      bf16x8 ka0 = *(const bf16x8*)&Ktile[cur][krow * 64 + ks0];
      bf16x8 ka1 = *(const bf16x8*)&Ktile[cur][krow * 64 + ks1];
      f32x4 acc = {};
      acc = MFMA16(ka0, qa0, acc, 0, 0, 0);
      acc = MFMA16(ka1, qa1, acc, 0, 0, 0);
      const int kc = kb + t * 16 + 4 * lh;
      f32x4 s = score4(acc, qrow, kc, mrow, rbh, rb_lo, rb_hi, um);
      f32x4 p;
#pragma unroll
      for (int j = 0; j < 4; ++j) p[j] = __expf(s[j] - M) * invs;
      *(f32x4*)&S_lds[w][lr][t * 16 + 4 * lh] = p;
    }
#pragma unroll
    for (int i = 0; i < 4; ++i) {
      const int row = 4 * i + lh;
      f32x4 pv = *(const f32x4*)&S_lds[w][row][lr * 4];
      __builtin_nontemporal_store(pv, (f32x4*)&Abase[(size_t)row * S_N + kb + lr * 4]);
    }
#pragma unroll
    for (int ch = 0; ch < 2; ++ch) {
      f32x8 pf = *(const f32x8*)&S_lds[w][lr][ch * 32 + lh * 8];
      bf16x8 pa;
#pragma unroll
      for (int j = 0; j < 8; ++j) pa[j] = f2b(pf[j]);
#pragma unroll
      for (int dt = 0; dt < 4; ++dt) {
        const int drow = dt * 16 + lr;
        bf16x8 vb = *(const bf16x8*)&Vtile[cur][drow * 64 + (((ch * 4 + lh) ^ (lr & 7)) * 8)];
        accp[dt] = MFMA16(pa, vb, accp[dt], 0, 0, 0);    // D[q][d]
      }
    }
    if (kt + 1 < 16) {
      *(bf16x8*)&Ktile[cur ^ 1][sg_row * 64 + sg_s] = krn;
      *(bf16x8*)&Vtile[cur ^ 1][sg_row * 64 + sg_s] = vrn;
    }
    lds_barrier();
  }
#pragma unroll
  for (int dt = 0; dt < 4; ++dt)
#pragma unroll
    for (int r = 0; r < 4; ++r)
      ctx[((size_t)(b * S_N + q0 + w * 16 + 4 * lh + r)) * E_N + h * 64 + dt * 16 + lr] =
          f2b(accp[dt][r]);
}

// ---------------------------------------------------------------------------
extern "C" void kernel_launch(void* const* d_in, const int* in_sizes, int n_in,
                              void* d_out, int out_size, void* d_ws, size_t ws_size,
                              hipStream_t stream) {
  (void)in_sizes; (void)n_in; (void)out_size; (void)ws_size;
  const float* query = (const float*)d_in[0];
  const float* key   = (const float*)d_in[1];
  const float* value = (const float*)d_in[2];
  const unsigned char* mask = (const unsigned char*)d_in[3];
  const float* Wq = (const float*)d_in[4];
  const float* bq = (const float*)d_in[5];
  const float* Wk = (const float*)d_in[6];
  const float* bk = (const float*)d_in[7];
  const float* Wv = (const float*)d_in[8];
  const float* bv = (const float*)d_in[9];
  const float* Wo = (const float*)d_in[10];
  const float* bo = (const float*)d_in[11];
  const float* rel_bias = (const float*)d_in[12];

  float* out_f    = (float*)d_out;                     //  4,194,304 floats
  float* attn_f   = out_f + (size_t)4194304;           // 67,108,864 floats
  float* scores_f = attn_f + (size_t)67108864;         // 67,108,864 floats

  char* ws = (char*)d_ws;                              // ~2GiB; 65MB used
  bf16_t* qbf  = (bf16_t*)(ws);                        // (4096,1024) 8MB
  bf16_t* kbf  = (bf16_t*)(ws + (8ull  << 20));        // 8MB
  bf16_t* vbf  = (bf16_t*)(ws + (16ull << 20));        // 8MB
  bf16_t* Wqb  = (bf16_t*)(ws + (24ull << 20));        // 2MB
  bf16_t* Wkb  = (bf16_t*)(ws + (26ull << 20));        // 2MB
  bf16_t* Wvb  = (bf16_t*)(ws + (28ull << 20));        // 2MB
  bf16_t* Wob  = (bf16_t*)(ws + (30ull << 20));        // 2MB
  bf16_t* Qbf  = (bf16_t*)(ws + (32ull << 20));        // (B,H,S,D) 8MB
  bf16_t* Kbf  = (bf16_t*)(ws + (40ull << 20));        // (B,H,S,D) 8MB
  bf16_t* Vtbf = (bf16_t*)(ws + (48ull << 20));        // (B,H,D,S) 8MB
  bf16_t* CTX  = (bf16_t*)(ws + (56ull << 20));        // (B,S,E)   8MB
  unsigned char* FLAGS = (unsigned char*)(ws + (64ull << 20)); // 4KB

  convert_kernel<<<dim3(8192), dim3(256), 0, stream>>>(
      query, key, value, Wq, Wk, Wv, Wo, qbf, kbf, vbf, Wqb, Wkb, Wvb, Wob);
  mask_rowany<<<dim3(1024), dim3(256), 0, stream>>>(mask, FLAGS);
  qkv_gemm<<<dim3(8, 32, 3), dim3(256), 0, stream>>>(
      qbf, kbf, vbf, Wqb, Wkb, Wvb, bq, bk, bv, Qbf, Kbf, Vtbf);
  fused_attn<<<dim3(4, 128), dim3(512), 0, stream>>>(
      Qbf, Kbf, Vtbf, mask, FLAGS, rel_bias, scores_f, attn_f, CTX);
  out_gemm<<<dim3(8, 64), dim3(256), 0, stream>>>(CTX, Wob, bo, out_f);
}